// Round 2
// baseline (3552.799 us; speedup 1.0000x reference)
//
#include <hip/hip_runtime.h>
#include <hip/hip_fp16.h>

#define BATCH 1024
#define SEQ   64
#define HID   128
#define GATES 512
#define TOUT  24

typedef unsigned int u32;

// fast sigmoid/tanh: v_exp + v_rcp, abs err ~1e-7 (fine vs 9.9e-4 budget)
static __device__ __forceinline__ float sigm(float x){
  return __builtin_amdgcn_rcpf(1.f + __expf(-x));
}
static __device__ __forceinline__ float tanh_fast(float x){
  return fmaf(2.f, __builtin_amdgcn_rcpf(1.f + __expf(-2.f*x)), -1.f);
}

// ---------------- per-wave GEMM slice ----------------
// wave kg handles k in [kg*KQ,(kg+1)*KQ); lane ng handles 8 gate cols:
// col(ng,c) = 2*ng + 128*(c>>1) + (c&1).  Weights pre-swizzled [k][ng][8] fp16.
__device__ __forceinline__ void gemm8(const __half* __restrict__ wsw, int KQ,
    const float* __restrict__ uTrow, float* __restrict__ gout, int ng)
{
  float acc[4][8];
#pragma unroll
  for (int r=0;r<4;++r)
#pragma unroll
    for (int j=0;j<8;++j) acc[r][j]=0.f;

  const __half* wp = wsw + ng*8;
  uint4 w0 = *(const uint4*)(wp);
  uint4 w1 = *(const uint4*)(wp + 512);
  const float4* up = (const float4*)uTrow;

  for (int kk=0; kk<KQ; kk+=2){
    uint4 nw0 = w0, nw1 = w1;
    if (kk+2 < KQ){                       // prefetch next 2 k-rows
      nw0 = *(const uint4*)(wp + 1024);
      nw1 = *(const uint4*)(wp + 1536);
    }
    float4 u0 = up[kk];
    float4 u1 = up[kk+1];
    float us0[4] = {u0.x, u0.y, u0.z, u0.w};
    float us1[4] = {u1.x, u1.y, u1.z, u1.w};
    const __half2* h0 = (const __half2*)&w0;
    const __half2* h1 = (const __half2*)&w1;
#pragma unroll
    for (int p=0;p<4;++p){
      float2 wa = __half22float2(h0[p]);
      float2 wb = __half22float2(h1[p]);
#pragma unroll
      for (int r=0;r<4;++r){
        acc[r][2*p]   = fmaf(us0[r], wa.x, acc[r][2*p]);
        acc[r][2*p+1] = fmaf(us0[r], wa.y, acc[r][2*p+1]);
        acc[r][2*p]   = fmaf(us1[r], wb.x, acc[r][2*p]);
        acc[r][2*p+1] = fmaf(us1[r], wb.y, acc[r][2*p+1]);
      }
    }
    w0 = nw0; w1 = nw1; wp += 1024;
  }
#pragma unroll
  for (int r=0;r<4;++r)
#pragma unroll
    for (int m=0;m<4;++m)
      *(float2*)(gout + r*520 + 2*ng + 128*m) = make_float2(acc[r][2*m], acc[r][2*m+1]);
}

// NC=2 variant for the hproj GEMM (N=128): col(ng,c) = 2*ng + c, weights [k][ng][2]
__device__ __forceinline__ void gemm2(const __half* __restrict__ wsw, int KQ,
    const float* __restrict__ uTrow, float* __restrict__ gout, int ng)
{
  float acc[4][2];
#pragma unroll
  for (int r=0;r<4;++r){ acc[r][0]=0.f; acc[r][1]=0.f; }

  const __half* wp = wsw + ng*2;
  u32 w0 = *(const u32*)(wp);
  u32 w1 = *(const u32*)(wp + 128);
  const float4* up = (const float4*)uTrow;

  for (int kk=0; kk<KQ; kk+=2){
    u32 nw0 = w0, nw1 = w1;
    if (kk+2 < KQ){
      nw0 = *(const u32*)(wp + 256);
      nw1 = *(const u32*)(wp + 384);
    }
    float4 u0 = up[kk];
    float4 u1 = up[kk+1];
    float us0[4] = {u0.x, u0.y, u0.z, u0.w};
    float us1[4] = {u1.x, u1.y, u1.z, u1.w};
    float2 wa = __half22float2(*(const __half2*)&w0);
    float2 wb = __half22float2(*(const __half2*)&w1);
#pragma unroll
    for (int r=0;r<4;++r){
      acc[r][0] = fmaf(us0[r], wa.x, acc[r][0]);
      acc[r][1] = fmaf(us0[r], wa.y, acc[r][1]);
      acc[r][0] = fmaf(us1[r], wb.x, acc[r][0]);
      acc[r][1] = fmaf(us1[r], wb.y, acc[r][1]);
    }
    w0 = nw0; w1 = nw1; wp += 256;
  }
#pragma unroll
  for (int r=0;r<4;++r)
    *(float2*)(gout + r*520 + 2*ng) = make_float2(acc[r][0], acc[r][1]);
}

// ---------------- weight prep: fp32 -> swizzled fp16 ----------------
__global__ void prep_kernel(
    const float* __restrict__ eWih0, const float* __restrict__ eWhh0,
    const float* __restrict__ eWih12, const float* __restrict__ eWhh12,
    const float* __restrict__ aW,
    const float* __restrict__ dWih0, const float* __restrict__ dWhh0,
    const float* __restrict__ dWih12, const float* __restrict__ dWhh12,
    const float* __restrict__ oW,
    __half* __restrict__ wE0, __half* __restrict__ wE1, __half* __restrict__ wE2,
    __half* __restrict__ wD0, __half* __restrict__ wD1, __half* __restrict__ wD2,
    __half* __restrict__ wAh, float* __restrict__ wAe, float* __restrict__ wOT)
{
  int id = blockIdx.x * blockDim.x + threadIdx.x;
  const int nE0 = 136*512, nE12 = 256*512, nD0 = 264*512, nAh = 128*128, nAe = 128*128, nOT = 512;

  if (id < nE0){
    int k = id >> 9, q = id & 511, ng = q >> 3, c = q & 7;
    int n = 2*ng + 128*(c>>1) + (c&1);
    float v = 0.f;
    if (k < 2) v = eWih0[n*2 + k];
    else if (k < 130) v = eWhh0[n*128 + (k-2)];
    wE0[id] = __float2half(v);
    return;
  }
  id -= nE0;
  if (id < 2*nE12){
    int l = id / nE12, m = id % nE12;
    int k = m >> 9, q = m & 511, ng = q >> 3, c = q & 7;
    int n = 2*ng + 128*(c>>1) + (c&1);
    const float* Wi = eWih12 + (size_t)l*GATES*HID;
    const float* Wh = eWhh12 + (size_t)l*GATES*HID;
    float v = (k < 128) ? Wi[n*128 + k] : Wh[n*128 + (k-128)];
    (l ? wE2 : wE1)[m] = __float2half(v);
    return;
  }
  id -= 2*nE12;
  if (id < nD0){
    int k = id >> 9, q = id & 511, ng = q >> 3, c = q & 7;
    int n = 2*ng + 128*(c>>1) + (c&1);
    float v = 0.f;
    if (k < 130) v = dWih0[n*130 + k];           // [prev_out(2), weighted(128)]
    else if (k >= 136) v = dWhh0[n*128 + (k-136)]; // rows 130..135 zero pad
    wD0[id] = __float2half(v);
    return;
  }
  id -= nD0;
  if (id < 2*nE12){
    int l = id / nE12, m = id % nE12;
    int k = m >> 9, q = m & 511, ng = q >> 3, c = q & 7;
    int n = 2*ng + 128*(c>>1) + (c&1);
    const float* Wi = dWih12 + (size_t)l*GATES*HID;
    const float* Wh = dWhh12 + (size_t)l*GATES*HID;
    float v = (k < 128) ? Wi[n*128 + k] : Wh[n*128 + (k-128)];
    (l ? wD2 : wD1)[m] = __float2half(v);
    return;
  }
  id -= 2*nE12;
  if (id < nAh){                                  // attn_W[:, :H] transposed [k][n]
    int k = id >> 7, n = id & 127;
    wAh[id] = __float2half(aW[n*256 + k]);
    return;
  }
  id -= nAh;
  if (id < nAe){                                  // attn_W[:, H:] transposed, fp32
    int k = id >> 7, j = id & 127;
    wAe[id] = aW[j*256 + 128 + k];
    return;
  }
  id -= nAe;
  if (id < nOT){                                  // out_W transposed [k][2], fp32
    int k = id >> 1, j = id & 1;
    wOT[id] = oW[j*256 + k];
    return;
  }
}

// ---------------- main persistent kernel: 256 blocks, 4 batch rows each ----------------
__global__ __launch_bounds__(256, 1) void seq2seq_main(
    const float* __restrict__ x, const float* __restrict__ prev_y,
    const float* __restrict__ enc_b0, const float* __restrict__ enc_b12,
    const float* __restrict__ attn_b, const float* __restrict__ vW,
    const float* __restrict__ dec_b0, const float* __restrict__ dec_b12,
    const float* __restrict__ out_b,
    __half* __restrict__ hsA, __half* __restrict__ hsB, __half* __restrict__ hsC,
    const __half* __restrict__ wE0, const __half* __restrict__ wE1, const __half* __restrict__ wE2,
    const __half* __restrict__ wD0, const __half* __restrict__ wD1, const __half* __restrict__ wD2,
    const __half* __restrict__ wAh, const float* __restrict__ wAe, const float* __restrict__ wOT,
    float* __restrict__ dout)
{
  // uT row map (decoder): 0..1 prev_out | 2..129 weighted | 130..135 pad0 |
  //   136..263 h0 | 264..391 h1 | 392..519 h2
  // encoder l0: 0..1 x_t | 2..129 h | 130..135 pad ; l1/l2: 0..127 in | 128..255 h
  __shared__ __align__(16) float uT[520][4];
  __shared__ __align__(16) float gpart[16][520];  // [kg*4+r][col], pad 520 vs 512
  __shared__ float cstate[3][4*HID];
  __shared__ float hstate[3][4*HID];
  __shared__ __align__(16) __half hp16[4*HID];
  __shared__ float sc[4][64];
  extern __shared__ __align__(16) __half ep16[];  // [4][64][136] fp16 enc-side proj

  const int tid  = threadIdx.x;
  const int r    = tid >> 6;     // wave = batch row within block
  const int lane = tid & 63;
  const int kg   = r;            // wave doubles as k-group in GEMMs
  const int ng   = lane;
  const int b    = blockIdx.x*4 + r;

  if (tid < 24) uT[130 + (tid>>2)][tid&3] = 0.f;  // zero pad rows

  // ================= encoder: 3 LSTM layers =================
  const __half* encW[3]  = {wE0, wE1, wE2};
  const float* encB[3]   = {enc_b0, enc_b12, enc_b12 + 512};
  const int encKp[3]     = {136, 256, 256};
  const int encKoh[3]    = {2, 128, 128};
  const __half* hsin3[3] = {nullptr, hsA, hsB};
  __half* hsout3[3]      = {hsA, hsB, hsC};

  auto lstm_pw = [&](int l, int koh, const float* __restrict__ bias,
                     __half* hsout, int t, bool save_h){
    const float* gp = &gpart[0][0];
    int jj = lane;
#pragma unroll
    for (int hh=0; hh<2; ++hh, jj+=64){
      float gi = gp[(0+r)*520+jj    ] + gp[(4+r)*520+jj    ] + gp[(8+r)*520+jj    ] + gp[(12+r)*520+jj    ] + bias[jj];
      float gf = gp[(0+r)*520+jj+128] + gp[(4+r)*520+jj+128] + gp[(8+r)*520+jj+128] + gp[(12+r)*520+jj+128] + bias[jj+128];
      float gg = gp[(0+r)*520+jj+256] + gp[(4+r)*520+jj+256] + gp[(8+r)*520+jj+256] + gp[(12+r)*520+jj+256] + bias[jj+256];
      float go = gp[(0+r)*520+jj+384] + gp[(4+r)*520+jj+384] + gp[(8+r)*520+jj+384] + gp[(12+r)*520+jj+384] + bias[jj+384];
      float c0 = cstate[l][r*HID + jj];
      float cn = fmaf(sigm(gf), c0, sigm(gi)*tanh_fast(gg));
      float hn = sigm(go)*tanh_fast(cn);
      cstate[l][r*HID + jj] = cn;
      uT[koh + jj][r] = hn;
      if (hsout) hsout[((size_t)b*SEQ + t)*HID + jj] = __float2half(hn);
      if (save_h) hstate[l][r*HID + jj] = hn;
    }
  };

  for (int layer=0; layer<3; ++layer){
    const __half* W  = encW[layer];
    const float* bias = encB[layer];
    const int Kp  = encKp[layer];
    const int KQ  = Kp >> 2;
    const int koh = encKoh[layer];
    const __half* hsin = hsin3[layer];
    __half* hsout = hsout3[layer];

    __syncthreads();                 // previous layer fully done
    uT[koh + lane][r] = 0.f;         // h = 0
    uT[koh + 64 + lane][r] = 0.f;
    cstate[layer][r*HID + lane] = 0.f;
    cstate[layer][r*HID + 64 + lane] = 0.f;

    float xv = 0.f; u32 hv = 0u;     // prefetch t=0 input
    if (layer == 0){ if (lane < 2) xv = x[((size_t)b*SEQ + 0)*2 + lane]; }
    else hv = *(const u32*)(hsin + ((size_t)b*SEQ + 0)*HID + 2*lane);

    for (int t=0; t<SEQ; ++t){
      if (layer == 0){ if (lane < 2) uT[lane][r] = xv; }
      else {
        float2 f = __half22float2(*(const __half2*)&hv);
        uT[2*lane][r] = f.x; uT[2*lane+1][r] = f.y;
      }
      __syncthreads();               // uT ready (inputs + prev-step h)
      if (t+1 < SEQ){                // prefetch next-step input (hidden under GEMM)
        if (layer == 0){ if (lane < 2) xv = x[((size_t)b*SEQ + t+1)*2 + lane]; }
        else hv = *(const u32*)(hsin + ((size_t)b*SEQ + t+1)*HID + 2*lane);
      }
      gemm8(W + (size_t)(kg*KQ)*512, KQ, &uT[kg*KQ][0], &gpart[kg*4][0], ng);
      __syncthreads();               // gpart ready
      lstm_pw(layer, koh, bias, hsout, t, t == SEQ-1);
    }
  }
  __syncthreads();                   // encoder done; hsC (enc_out) drained

  // ================= enc-side attention projection (once) =================
  // ep16[r][s][j] = sum_d enc_out[b][s][d]*attn_W[j][128+d] + attn_b[j]
  {
    const int s = lane;
    const u32* arow = (const u32*)(hsC + ((size_t)b*SEQ + s)*HID);
    u32 a[64];                       // 64 u32 = 128 halfs = full 256 B row
#pragma unroll
    for (int i=0;i<16;++i){
      uint4 v = ((const uint4*)arow)[i];
      a[4*i]=v.x; a[4*i+1]=v.y; a[4*i+2]=v.z; a[4*i+3]=v.w;
    }
#pragma unroll
    for (int jc=0; jc<2; ++jc){
      float acc[64];
#pragma unroll
      for (int j=0;j<64;++j) acc[j] = attn_b[jc*64 + j];
      for (int kp=0; kp<64; ++kp){
        float2 af = __half22float2(*(const __half2*)&a[kp]);
        const float* w0 = wAe + (size_t)(2*kp)*HID + jc*64;
        const float* w1 = w0 + HID;
#pragma unroll
        for (int j=0;j<64;++j) acc[j] = fmaf(af.x, w0[j], acc[j]);
#pragma unroll
        for (int j=0;j<64;++j) acc[j] = fmaf(af.y, w1[j], acc[j]);
      }
      __half2* eprow = (__half2*)&ep16[(size_t)(r*64 + s)*136 + jc*64];
#pragma unroll
      for (int p=0;p<32;++p) eprow[p] = __floats2half2_rn(acc[2*p], acc[2*p+1]);
    }
  }

  // ================= decoder setup =================
  if (tid < 24) uT[130 + (tid>>2)][tid&3] = 0.f;  // re-zero pad0 (clobbered by l1/l2 h)
  uT[136 + lane][r]      = hstate[0][r*HID + lane];
  uT[136 + 64 + lane][r] = hstate[0][r*HID + 64 + lane];
  uT[264 + lane][r]      = hstate[1][r*HID + lane];
  uT[264 + 64 + lane][r] = hstate[1][r*HID + 64 + lane];
  uT[392 + lane][r]      = hstate[2][r*HID + lane];
  uT[392 + 64 + lane][r] = hstate[2][r*HID + 64 + lane];
  if (lane < 2) uT[lane][r] = prev_y[b*2 + lane];
  __syncthreads();

  // ================= decoder: 24 autoregressive steps =================
  for (int t=0; t<TOUT; ++t){
    // hproj = attn_W[:,:H] @ h2   (h2 = uT rows 392..519)
    gemm2(wAh + (size_t)(kg*32)*128, 32, &uT[392 + kg*32][0], &gpart[kg*4][0], ng);
    __syncthreads();
    {
      const float* gp = &gpart[0][0];
      int jj = lane;
#pragma unroll
      for (int hh=0; hh<2; ++hh, jj+=64){
        float v = gp[(0+r)*520+jj] + gp[(4+r)*520+jj] + gp[(8+r)*520+jj] + gp[(12+r)*520+jj];
        hp16[r*HID + jj] = __float2half(v);
      }
    }
    __syncthreads();

    // scores + softmax (lane = source position s, all in registers)
    float score = 0.f;
    {
      const __half2* eprow = (const __half2*)&ep16[(size_t)(r*64 + lane)*136];
      const __half2* hprow = (const __half2*)&hp16[r*HID];
#pragma unroll 4
      for (int p=0; p<64; ++p){
        float2 e = __half22float2(eprow[p]);
        float2 h = __half22float2(hprow[p]);
        score = fmaf(tanh_fast(e.x + h.x), vW[2*p],   score);
        score = fmaf(tanh_fast(e.y + h.y), vW[2*p+1], score);
      }
    }
    float mx = score;
#pragma unroll
    for (int off=32; off; off>>=1) mx = fmaxf(mx, __shfl_xor(mx, off));
    float ev = __expf(score - mx);
    float sm = ev;
#pragma unroll
    for (int off=32; off; off>>=1) sm += __shfl_xor(sm, off);
    sc[r][lane] = ev / sm;
    __syncthreads();

    // weighted = attw @ enc_out  -> uT rows 2..129 (lane = d-pair)
    {
      const u32* ebase = (const u32*)(hsC) + ((size_t)b*SEQ)*64 + lane;
      float a0 = 0.f, a1 = 0.f;
#pragma unroll 8
      for (int s2=0; s2<64; ++s2){
        float w = sc[r][s2];
        float2 af = __half22float2(*(const __half2*)&ebase[(size_t)s2*64]);
        a0 = fmaf(w, af.x, a0); a1 = fmaf(w, af.y, a1);
      }
      uT[2 + 2*lane][r] = a0;
      uT[3 + 2*lane][r] = a1;
    }
    __syncthreads();

    // 3 decoder LSTM cells
    gemm8(wD0 + (size_t)(kg*66)*512, 66, &uT[0 + kg*66][0], &gpart[kg*4][0], ng);
    __syncthreads();
    lstm_pw(0, 136, dec_b0, nullptr, 0, false);
    __syncthreads();
    gemm8(wD1 + (size_t)(kg*64)*512, 64, &uT[136 + kg*64][0], &gpart[kg*4][0], ng);
    __syncthreads();
    lstm_pw(1, 264, dec_b12, nullptr, 0, false);
    __syncthreads();
    gemm8(wD2 + (size_t)(kg*64)*512, 64, &uT[264 + kg*64][0], &gpart[kg*4][0], ng);
    __syncthreads();
    lstm_pw(2, 392, dec_b12 + 512, nullptr, 0, false);
    __syncthreads();

    // out = [h2, weighted] @ out_W^T + out_b
    {
      float o0 = 0.f, o1 = 0.f;
#pragma unroll
      for (int q=0; q<4; ++q){
        int k = lane*4 + q;
        float uv = (k < 128) ? uT[392 + k][r] : uT[2 + (k-128)][r];
        float2 w = ((const float2*)wOT)[k];
        o0 = fmaf(uv, w.x, o0);
        o1 = fmaf(uv, w.y, o1);
      }
#pragma unroll
      for (int off=32; off; off>>=1){ o0 += __shfl_down(o0, off); o1 += __shfl_down(o1, off); }
      if (lane == 0){
        float v0 = o0 + out_b[0], v1 = o1 + out_b[1];
        size_t oidx = ((size_t)t*BATCH + b)*2;
        dout[oidx] = v0; dout[oidx+1] = v1;
        uT[0][r] = v0; uT[1][r] = v1;   // prev_out for next step
      }
    }
    __syncthreads();
  }
}

extern "C" void kernel_launch(void* const* d_in, const int* in_sizes, int n_in,
                              void* d_out, int out_size, void* d_ws, size_t ws_size,
                              hipStream_t stream) {
  const float* x      = (const float*)d_in[0];
  const float* prev_y = (const float*)d_in[1];
  const float* eWih0  = (const float*)d_in[2];
  const float* eWhh0  = (const float*)d_in[3];
  const float* eb0    = (const float*)d_in[4];
  const float* eWih12 = (const float*)d_in[5];
  const float* eWhh12 = (const float*)d_in[6];
  const float* eb12   = (const float*)d_in[7];
  const float* aW     = (const float*)d_in[8];
  const float* ab     = (const float*)d_in[9];
  const float* vW     = (const float*)d_in[10];
  const float* dWih0  = (const float*)d_in[11];
  const float* dWhh0  = (const float*)d_in[12];
  const float* db0    = (const float*)d_in[13];
  const float* dWih12 = (const float*)d_in[14];
  const float* dWhh12 = (const float*)d_in[15];
  const float* db12   = (const float*)d_in[16];
  const float* oW     = (const float*)d_in[17];
  const float* ob     = (const float*)d_in[18];

  // ws layout: weights FIRST (small, critical), then activation buffers.
  __half* wE0 = (__half*)d_ws;
  __half* wE1 = wE0 + 136*512;
  __half* wE2 = wE1 + 256*512;
  __half* wD0 = wE2 + 256*512;
  __half* wD1 = wD0 + 264*512;
  __half* wD2 = wD1 + 256*512;
  __half* wAh = wD2 + 256*512;
  float*  wAe = (float*)(wAh + 128*128);
  float*  wOT = wAe + 128*128;
  __half* hsA = (__half*)(wOT + 512);
  __half* hsB = hsA + (size_t)BATCH*SEQ*HID;
  __half* hsC = hsA;   // layer-0 data dead once layer 1 done; per-block regions disjoint

  const int prepN = 136*512 + 2*256*512 + 264*512 + 2*256*512 + 128*128 + 128*128 + 512;
  prep_kernel<<<(prepN + 255)/256, 256, 0, stream>>>(
      eWih0, eWhh0, eWih12, eWhh12, aW, dWih0, dWhh0, dWih12, dWhh12, oW,
      wE0, wE1, wE2, wD0, wD1, wD2, wAh, wAe, wOT);

  const int dynBytes = 4*64*136*2;   // ep16: 69,632 B
  hipFuncSetAttribute(reinterpret_cast<const void*>(seq2seq_main),
                      hipFuncAttributeMaxDynamicSharedMemorySize, dynBytes);

  seq2seq_main<<<256, 256, dynBytes, stream>>>(
      x, prev_y, eb0, eb12, ab, vW, db0, db12, ob,
      hsA, hsB, hsC, wE0, wE1, wE2, wD0, wD1, wD2, wAh, wAe, wOT,
      (float*)d_out);
}

// Round 3
// 1548.202 us; speedup vs baseline: 2.2948x; 2.2948x over previous
//
#include <hip/hip_runtime.h>
#include <hip/hip_fp16.h>

#define BATCH 1024
#define SEQ   64
#define HID   128
#define TOUT  24
#define EPS   132   // ep16 row stride (halfs) — 132 => 2-way-max LDS banking on score reads

typedef unsigned int u32;
typedef _Float16 f16;
typedef __attribute__((ext_vector_type(8))) f16 f16x8;
typedef __attribute__((ext_vector_type(4))) float f32x4;

static __device__ __forceinline__ float sigm(float x){
  return __builtin_amdgcn_rcpf(1.f + __expf(-x));
}
static __device__ __forceinline__ float tanh_fast(float x){
  return fmaf(2.f, __builtin_amdgcn_rcpf(1.f + __expf(-2.f*x)), -1.f);
}
// half-index of element (row m in 0..3, k) in an MFMA A-fragment LDS buffer.
// Fragment layout: lane l reads 16B at (ktile*64+l)*16; element (m,k):
// lane = m + ((k>>3)&3)*16, slot j = k&7  ->  conflict-free b128 reads.
static __device__ __forceinline__ int slotk(int r, int k){
  return ((k>>5)*64 + r + ((k>>3)&3)*16)*8 + (k&7);
}

// ---- MFMA gate GEMM: D[16(4 real)x512] = A[16xK] * B[Kx512], wave w owns ntiles w*4..w*4+3
template<int KT>
static __device__ __forceinline__ void mfma_gates(const __half* __restrict__ W,
    const __half* __restrict__ A, float* __restrict__ gpre, int lane, int w)
{
  f16x8 a[KT];
#pragma unroll
  for (int kt=0; kt<KT; ++kt) a[kt] = *(const f16x8*)(A + (kt*64 + lane)*8);
  const f16x8* wb = (const f16x8*)W + (size_t)(w*4*KT)*64 + lane;
  f16x8 Bf[4*KT];
#pragma unroll
  for (int i=0; i<4*KT; ++i) Bf[i] = wb[(size_t)i*64];   // deep load queue
#pragma unroll
  for (int nt=0; nt<4; ++nt){
    f32x4 acc = {0.f,0.f,0.f,0.f};
#pragma unroll
    for (int kt=0; kt<KT; ++kt)
      acc = __builtin_amdgcn_mfma_f32_16x16x32_f16(a[kt], Bf[nt*KT+kt], acc, 0,0,0);
    if (lane < 16){                       // lanes 0-15 hold rows 0-3 (regs 0-3), col=lane
      int col = (w*4+nt)*16 + lane;
#pragma unroll
      for (int q=0; q<4; ++q) gpre[q*512 + col] = acc[q];
    }
  }
}

// ---- hproj: D[16x128] = h2[16x128] * attn_Wh[128x128]; wave w owns ntile w; A = Ad2 ktiles 4..7
static __device__ __forceinline__ void mfma_hproj(const __half* __restrict__ W,
    const __half* __restrict__ A, float* __restrict__ gpre, int lane, int w)
{
  f16x8 a[4], Bf[4];
#pragma unroll
  for (int kt=0; kt<4; ++kt) a[kt] = *(const f16x8*)(A + ((4+kt)*64 + lane)*8);
  const f16x8* wb = (const f16x8*)W + (size_t)(w*4)*64 + lane;
#pragma unroll
  for (int kt=0; kt<4; ++kt) Bf[kt] = wb[(size_t)kt*64];
  f32x4 acc = {0.f,0.f,0.f,0.f};
#pragma unroll
  for (int kt=0; kt<4; ++kt)
    acc = __builtin_amdgcn_mfma_f32_16x16x32_f16(a[kt], Bf[kt], acc, 0,0,0);
  if (lane < 16){
    int col = w*16 + lane;
#pragma unroll
    for (int q=0; q<4; ++q) gpre[q*512 + col] = acc[q];
  }
}

// ---------------- weight prep: fp32 -> MFMA B-fragment fp16 layouts ----------------
// B-frag: element (col = nt*16 + (l&15), k = kt*32 + (l>>4)*8 + j) at [nt][kt][l][j]
__global__ void prep_kernel(
    const float* __restrict__ eWih0,  const float* __restrict__ eWhh0,
    const float* __restrict__ eWih12, const float* __restrict__ eWhh12,
    const float* __restrict__ aW,
    const float* __restrict__ dWih0,  const float* __restrict__ dWhh0,
    const float* __restrict__ dWih12, const float* __restrict__ dWhh12,
    const float* __restrict__ oW,
    __half* __restrict__ wE0, __half* __restrict__ wE1, __half* __restrict__ wE2,
    __half* __restrict__ wD0, __half* __restrict__ wD1, __half* __restrict__ wD2,
    __half* __restrict__ wAh, float* __restrict__ wAe, float* __restrict__ wOT,
    float* __restrict__ dW2)
{
  int id = blockIdx.x*blockDim.x + threadIdx.x;
  if (id < 65536){                                   // wE0: K=128 (h only), KT=4
    int m=id, j=m&7, l=(m>>3)&63, kt=(m>>9)&3, nt=m>>11;
    int col = nt*16 + (l&15), k = kt*32 + ((l>>4)<<3) + j;
    wE0[m] = __float2half(eWhh0[col*128 + k]); return;
  }
  id -= 65536;
  if (id < 5*131072){                                // wE1,wE2,wD0,wD1,wD2: K=256, KT=8
    int seg = id >> 17, m = id & 131071;
    int j=m&7, l=(m>>3)&63, kt=(m>>9)&7, nt=m>>12;
    int col = nt*16 + (l&15), k = kt*32 + ((l>>4)<<3) + j;
    float v;
    if (seg==0)      v = (k<128)? eWih12[col*128+k]         : eWhh12[col*128 + (k-128)];
    else if (seg==1) v = (k<128)? eWih12[65536+col*128+k]   : eWhh12[65536 + col*128 + (k-128)];
    else if (seg==2) v = (k<128)? dWih0[col*130 + 2 + k]    : dWhh0[col*128 + (k-128)];
    else if (seg==3) v = (k<128)? dWih12[col*128+k]         : dWhh12[col*128 + (k-128)];
    else             v = (k<128)? dWih12[65536+col*128+k]   : dWhh12[65536 + col*128 + (k-128)];
    __half* dst = (seg==0)?wE1:(seg==1)?wE2:(seg==2)?wD0:(seg==3)?wD1:wD2;
    dst[m] = __float2half(v); return;
  }
  id -= 5*131072;
  if (id < 16384){                                   // wAh: attn_W[:, :H], K=128, N=128, KT=4 NT=8
    int m=id, j=m&7, l=(m>>3)&63, kt=(m>>9)&3, nt=m>>11;
    int col = nt*16 + (l&15), k = kt*32 + ((l>>4)<<3) + j;
    wAh[m] = __float2half(aW[col*256 + k]); return;
  }
  id -= 16384;
  if (id < 16384){ int k=id>>7, jq=id&127; wAe[id] = aW[jq*256 + 128 + k]; return; }  // [k][j] f32
  id -= 16384;
  if (id < 512){ int k=id>>1, jo=id&1; wOT[id] = oW[jo*256 + k]; return; }            // [k][2] f32
  id -= 512;
  if (id < 1024){ int col=id>>1, ki=id&1; dW2[id] = dWih0[col*130 + ki]; return; }    // [col][2] f32
}

// ---------------- main persistent kernel: 256 blocks x 512 thr, 4 batch rows each ----------------
__global__ __launch_bounds__(512, 2) void seq2seq_main(
    const float* __restrict__ x, const float* __restrict__ prev_y,
    const float* __restrict__ enc_b0, const float* __restrict__ enc_b12,
    const float* __restrict__ attn_b, const float* __restrict__ vW,
    const float* __restrict__ dec_b0, const float* __restrict__ dec_b12,
    const float* __restrict__ out_b, const float* __restrict__ eWih0,
    __half* __restrict__ hsA, __half* __restrict__ hsB,
    const __half* __restrict__ wE0, const __half* __restrict__ wE1, const __half* __restrict__ wE2,
    const __half* __restrict__ wD0, const __half* __restrict__ wD1, const __half* __restrict__ wD2,
    const __half* __restrict__ wAh, const float* __restrict__ wAe, const float* __restrict__ wOT,
    const float* __restrict__ dW2, float* __restrict__ dout)
{
  __shared__ __align__(16) __half Aenc[2048];                 // [8 ktiles][64 lanes][8]
  __shared__ __align__(16) __half Ad0[2048], Ad1[2048], Ad2[2048];
  __shared__ __align__(16) float gpre[4*512];                 // [r][512] gate preacts
  __shared__ __align__(16) float hw[4*256];                   // [r][h2(128)|weighted(128)]
  __shared__ __align__(16) float cst[3][4*128];
  __shared__ float scb[4][64];
  __shared__ float xc[2][4][2];
  __shared__ float po[4][2];
  __shared__ float vwl[128];
  extern __shared__ __align__(16) __half ep16[];              // [4*64][EPS]

  const int tid  = threadIdx.x;
  const int w    = tid >> 6;
  const int lane = tid & 63;
  const int rr   = tid >> 6;       // r for tid<256 phases
  const int b4   = blockIdx.x * 4;

  // pointwise LSTM cell for 2 adjacent h-cols (j, j+1)
  auto cellpw = [&](int r, int j, const float* __restrict__ bias, float* __restrict__ crow,
                    const float* __restrict__ foldW, const float* __restrict__ fv,
                    __half* A1, int k1, __half* A2, int k2,
                    __half* hsd, float* hwd){
    const float* gpr = gpre + r*512;
    float2 g0 = *(const float2*)(gpr + j);
    float2 g1 = *(const float2*)(gpr + j + 128);
    float2 g2 = *(const float2*)(gpr + j + 256);
    float2 g3 = *(const float2*)(gpr + j + 384);
    float2 b0 = *(const float2*)(bias + j);
    float2 b1 = *(const float2*)(bias + j + 128);
    float2 b2 = *(const float2*)(bias + j + 256);
    float2 b3 = *(const float2*)(bias + j + 384);
    g0.x+=b0.x; g0.y+=b0.y; g1.x+=b1.x; g1.y+=b1.y;
    g2.x+=b2.x; g2.y+=b2.y; g3.x+=b3.x; g3.y+=b3.y;
    if (foldW){                                   // rank-2 input fold (x or prev_out)
      float a0=fv[0], a1=fv[1];
      float4 f0 = *(const float4*)(foldW + 2*j);
      float4 f1 = *(const float4*)(foldW + 2*j + 256);
      float4 f2 = *(const float4*)(foldW + 2*j + 512);
      float4 f3 = *(const float4*)(foldW + 2*j + 768);
      g0.x += a0*f0.x + a1*f0.y;  g0.y += a0*f0.z + a1*f0.w;
      g1.x += a0*f1.x + a1*f1.y;  g1.y += a0*f1.z + a1*f1.w;
      g2.x += a0*f2.x + a1*f2.y;  g2.y += a0*f2.z + a1*f2.w;
      g3.x += a0*f3.x + a1*f3.y;  g3.y += a0*f3.z + a1*f3.w;
    }
    float2 c = *(const float2*)(crow + j);
    float2 cn, hn;
    cn.x = fmaf(sigm(g1.x), c.x, sigm(g0.x)*tanh_fast(g2.x));
    cn.y = fmaf(sigm(g1.y), c.y, sigm(g0.y)*tanh_fast(g2.y));
    hn.x = sigm(g3.x)*tanh_fast(cn.x);
    hn.y = sigm(g3.y)*tanh_fast(cn.y);
    *(float2*)(crow + j) = cn;
    __half2 hh = __floats2half2_rn(hn.x, hn.y);
    if (A1)  *(__half2*)(A1 + slotk(r, k1 + j)) = hh;
    if (A2)  *(__half2*)(A2 + slotk(r, k2 + j)) = hh;
    if (hsd) *(__half2*)hsd = hh;
    if (hwd) *(float2*)(hwd + j) = make_float2(hn.x, hn.y);
  };

  // ================= encoder: 3 LSTM layers =================
  const __half* Wenc[3] = {wE0, wE1, wE2};
  const float*  Benc[3] = {enc_b0, enc_b12, enc_b12 + 512};
  const __half* hsIn[3] = {nullptr, hsA, hsB};
  __half* hsOut[3]      = {hsA, hsB, hsA};    // layer2 out aliases hsA (layer0 data dead)
  __half* Adl[3]        = {Ad0, Ad1, Ad2};

  for (int layer=0; layer<3; ++layer){
    const int koh = (layer==0) ? 0 : 128;
    if (tid < 256){
      int r = rr, j = 2*lane;
      *(__half2*)(Aenc + slotk(r, koh + j)) = __floats2half2_rn(0.f, 0.f);
      *(float2*)(&cst[layer][r*128 + j]) = make_float2(0.f, 0.f);
    } else {
      int idx = tid - 256;
      if (layer==0){
        if (idx < 8){ int r=idx>>1, xi=idx&1; xc[0][r][xi] = x[((size_t)(b4+r)*SEQ + 0)*2 + xi]; }
      } else {
        int r = idx>>6, dp = idx&63;
        u32 hv = *((const u32*)hsIn[layer] + ((size_t)(b4+r)*SEQ + 0)*64 + dp);
        *(u32*)(Aenc + slotk(r, 2*dp)) = hv;
      }
    }
    __syncthreads();
    for (int t=0; t<SEQ; ++t){
      if (layer==0) mfma_gates<4>(Wenc[0],     Aenc, gpre, lane, w);
      else          mfma_gates<8>(Wenc[layer], Aenc, gpre, lane, w);
      __syncthreads();
      if (tid < 256){
        int r = rr, j = 2*lane;
        __half* hsd = hsOut[layer] + ((size_t)(b4+r)*SEQ + t)*HID + j;
        cellpw(r, j, Benc[layer], &cst[layer][r*128],
               (layer==0)? eWih0 : nullptr, xc[t&1][r],
               Aenc, koh, (t==SEQ-1)? Adl[layer] : nullptr, 128, hsd, nullptr);
      } else {
        int idx = tid - 256;
        if (t+1 < SEQ){
          if (layer==0){
            if (idx < 8){ int r=idx>>1, xi=idx&1; xc[(t+1)&1][r][xi] = x[((size_t)(b4+r)*SEQ + t+1)*2 + xi]; }
          } else {
            int r = idx>>6, dp = idx&63;
            u32 hv = *((const u32*)hsIn[layer] + ((size_t)(b4+r)*SEQ + t+1)*64 + dp);
            *(u32*)(Aenc + slotk(r, 2*dp)) = hv;
          }
        }
      }
      __syncthreads();
    }
  }

  // ================= decoder setup + enc-side attention projection =================
  if (tid < 8){ po[tid>>1][tid&1] = prev_y[(b4 + (tid>>1))*2 + (tid&1)]; }
  if (tid < 128) vwl[tid] = vW[tid];
  {
    int rs = tid>>1, r = rs>>6, s = rs&63, jh = tid&1;
    const u32* arow = (const u32*)hsA + ((size_t)(b4+r)*SEQ + s)*64;
    u32 a[64];
#pragma unroll
    for (int i=0;i<16;++i){
      uint4 v = ((const uint4*)arow)[i];
      a[4*i]=v.x; a[4*i+1]=v.y; a[4*i+2]=v.z; a[4*i+3]=v.w;
    }
    float acc[64];
    const float* ab = attn_b + jh*64;
#pragma unroll
    for (int jq=0;jq<64;++jq) acc[jq] = ab[jq];
    for (int kp=0; kp<64; ++kp){
      float2 af = __half22float2(*(const __half2*)&a[kp]);
      const float* w0 = wAe + (size_t)(2*kp)*HID + jh*64;
      const float* w1 = w0 + HID;
#pragma unroll
      for (int jq=0;jq<64;++jq) acc[jq] = fmaf(af.x, w0[jq], acc[jq]);
#pragma unroll
      for (int jq=0;jq<64;++jq) acc[jq] = fmaf(af.y, w1[jq], acc[jq]);
    }
    __half2* ep = (__half2*)(ep16 + (size_t)rs*EPS + jh*64);
#pragma unroll
    for (int p=0;p<32;++p) ep[p] = __floats2half2_rn(acc[2*p], acc[2*p+1]);
  }
  __syncthreads();

  // ================= decoder: 24 autoregressive steps =================
  for (int t=0; t<TOUT; ++t){
    mfma_hproj(wAh, Ad2, gpre, lane, w);
    __syncthreads();
    {  // scores (512 thr: (r,s) pair, j split by jh)
      int rs = tid>>1, r = rs>>6, s = rs&63, jh = tid&1;
      const __half2* ep = (const __half2*)(ep16 + (size_t)rs*EPS + jh*64);
      const float* hp = gpre + r*512 + jh*64;
      float s_ = 0.f;
#pragma unroll
      for (int i=0;i<32;++i){
        float2 e = __half22float2(ep[i]);
        s_ = fmaf(tanh_fast(e.x + hp[2*i]),   vwl[jh*64 + 2*i],   s_);
        s_ = fmaf(tanh_fast(e.y + hp[2*i+1]), vwl[jh*64 + 2*i+1], s_);
      }
      s_ += __shfl_xor(s_, 1);
      if (jh==0) scb[r][s] = s_;
    }
    __syncthreads();
    if (tid < 256){   // softmax + weighted (wave r owns row r; in-wave ordering)
      float sv = scb[rr][lane];
      float mx = sv;
#pragma unroll
      for (int off=32; off; off>>=1) mx = fmaxf(mx, __shfl_xor(mx, off));
      float ev = __expf(sv - mx);
      float sm = ev;
#pragma unroll
      for (int off=32; off; off>>=1) sm += __shfl_xor(sm, off);
      scb[rr][lane] = ev / sm;
      const u32* eb = (const u32*)hsA + ((size_t)(b4+rr)*SEQ)*64 + lane;
      float a0=0.f, a1=0.f;
#pragma unroll 8
      for (int s2=0; s2<64; ++s2){
        float wgt = scb[rr][s2];
        float2 af = __half22float2(*(const __half2*)&eb[(size_t)s2*64]);
        a0 = fmaf(wgt, af.x, a0); a1 = fmaf(wgt, af.y, a1);
      }
      int j = 2*lane;
      *(__half2*)(Ad0 + slotk(rr, j)) = __floats2half2_rn(a0, a1);
      *(float2*)(hw + rr*256 + 128 + j) = make_float2(a0, a1);
    }
    __syncthreads();
    mfma_gates<8>(wD0, Ad0, gpre, lane, w);
    __syncthreads();
    if (tid < 256) cellpw(rr, 2*lane, dec_b0, &cst[0][rr*128], dW2, po[rr],
                          Ad0, 128, Ad1, 0, nullptr, nullptr);
    __syncthreads();
    mfma_gates<8>(wD1, Ad1, gpre, lane, w);
    __syncthreads();
    if (tid < 256) cellpw(rr, 2*lane, dec_b12, &cst[1][rr*128], nullptr, nullptr,
                          Ad1, 128, Ad2, 0, nullptr, nullptr);
    __syncthreads();
    mfma_gates<8>(wD2, Ad2, gpre, lane, w);
    __syncthreads();
    if (tid < 256) cellpw(rr, 2*lane, dec_b12 + 512, &cst[2][rr*128], nullptr, nullptr,
                          Ad2, 128, nullptr, 0, nullptr, hw + rr*256);
    __syncthreads();
    if (tid < 256){   // output head
      int r = rr;
      float4 hv = *(const float4*)(hw + r*256 + lane*4);
      float4 w0 = *(const float4*)(wOT + 8*lane);
      float4 w1 = *(const float4*)(wOT + 8*lane + 4);
      float o0 = hv.x*w0.x + hv.y*w0.z + hv.z*w1.x + hv.w*w1.z;
      float o1 = hv.x*w0.y + hv.y*w0.w + hv.z*w1.y + hv.w*w1.w;
#pragma unroll
      for (int off=32; off; off>>=1){ o0 += __shfl_down(o0,off); o1 += __shfl_down(o1,off); }
      if (lane==0){
        float v0 = o0 + out_b[0], v1 = o1 + out_b[1];
        size_t oi = ((size_t)t*BATCH + b4 + r)*2;
        dout[oi] = v0; dout[oi+1] = v1;
        po[r][0] = v0; po[r][1] = v1;
      }
    }
    __syncthreads();
  }
}

extern "C" void kernel_launch(void* const* d_in, const int* in_sizes, int n_in,
                              void* d_out, int out_size, void* d_ws, size_t ws_size,
                              hipStream_t stream) {
  const float* x      = (const float*)d_in[0];
  const float* prev_y = (const float*)d_in[1];
  const float* eWih0  = (const float*)d_in[2];
  const float* eWhh0  = (const float*)d_in[3];
  const float* eb0    = (const float*)d_in[4];
  const float* eWih12 = (const float*)d_in[5];
  const float* eWhh12 = (const float*)d_in[6];
  const float* eb12   = (const float*)d_in[7];
  const float* aW     = (const float*)d_in[8];
  const float* ab     = (const float*)d_in[9];
  const float* vW     = (const float*)d_in[10];
  const float* dWih0  = (const float*)d_in[11];
  const float* dWhh0  = (const float*)d_in[12];
  const float* db0    = (const float*)d_in[13];
  const float* dWih12 = (const float*)d_in[14];
  const float* dWhh12 = (const float*)d_in[15];
  const float* db12   = (const float*)d_in[16];
  const float* oW     = (const float*)d_in[17];
  const float* ob     = (const float*)d_in[18];

  __half* wE0 = (__half*)d_ws;           // 65536 halfs
  __half* wE1 = wE0 + 65536;             // 131072 each
  __half* wE2 = wE1 + 131072;
  __half* wD0 = wE2 + 131072;
  __half* wD1 = wD0 + 131072;
  __half* wD2 = wD1 + 131072;
  __half* wAh = wD2 + 131072;            // 16384
  float*  wAe = (float*)(wAh + 16384);   // 16384 f32
  float*  wOT = wAe + 16384;             // 512 f32
  float*  dW2 = wOT + 512;               // 1024 f32
  __half* hsA = (__half*)(dW2 + 1024);
  __half* hsB = hsA + (size_t)BATCH*SEQ*HID;

  const int prepN = 65536 + 5*131072 + 16384 + 16384 + 512 + 1024;
  prep_kernel<<<(prepN + 255)/256, 256, 0, stream>>>(
      eWih0, eWhh0, eWih12, eWhh12, aW, dWih0, dWhh0, dWih12, dWhh12, oW,
      wE0, wE1, wE2, wD0, wD1, wD2, wAh, wAe, wOT, dW2);

  const int dynBytes = 4*64*EPS*2;       // ep16: 67,584 B
  hipFuncSetAttribute(reinterpret_cast<const void*>(seq2seq_main),
                      hipFuncAttributeMaxDynamicSharedMemorySize, dynBytes);

  seq2seq_main<<<256, 512, dynBytes, stream>>>(
      x, prev_y, eb0, eb12, ab, vW, db0, db12, ob, eWih0,
      hsA, hsB, wE0, wE1, wE2, wD0, wD1, wD2, wAh, wAe, wOT, dW2,
      (float*)d_out);
}

// Round 4
// 1509.082 us; speedup vs baseline: 2.3543x; 1.0259x over previous
//
#include <hip/hip_runtime.h>
#include <hip/hip_fp16.h>

#define BATCH 1024
#define SEQ   64
#define HID   128
#define TOUT  24
#define EPS   132   // ep16 row stride (halfs)

typedef unsigned int u32;
typedef _Float16 f16;
typedef __attribute__((ext_vector_type(8))) f16 f16x8;
typedef __attribute__((ext_vector_type(4))) float f32x4;

static __device__ __forceinline__ float sigm(float x){
  return __builtin_amdgcn_rcpf(1.f + __expf(-x));
}
static __device__ __forceinline__ float tanh_fast(float x){
  return fmaf(2.f, __builtin_amdgcn_rcpf(1.f + __expf(-2.f*x)), -1.f);
}
// half-index of element (row m<4, k<128) inside ONE 2048-half A-fragment half-tile.
// lane = m + ((k>>3)&3)*16, slot j = k&7, ktile = k>>5  -> conflict-free b128 reads.
static __device__ __forceinline__ int slotk(int r, int k){
  return ((k>>5)*64 + r + ((k>>3)&3)*16)*8 + (k&7);
}

// ---- GEMM with register-resident weights: D[16x512] = A[16xK] * B[Kx512]
// wave w owns ntiles w*4..w*4+3; Bf = its weight slice (4*KT frags, nt-major)
template<int KT>
static __device__ __forceinline__ void mfma_gates_reg(const f16x8* Bf,
    const __half* __restrict__ A0, const __half* __restrict__ A1,
    float* __restrict__ gpre, int lane, int w)
{
  f16x8 a[KT];
#pragma unroll
  for (int kt=0; kt<KT; ++kt){
    const __half* src = (kt<4) ? (A0 + (kt*64+lane)*8) : (A1 + ((kt-4)*64+lane)*8);
    a[kt] = *(const f16x8*)src;
  }
#pragma unroll
  for (int nt=0; nt<4; ++nt){
    f32x4 acc = {0.f,0.f,0.f,0.f};
#pragma unroll
    for (int kt=0; kt<KT; ++kt)
      acc = __builtin_amdgcn_mfma_f32_16x16x32_f16(a[kt], Bf[nt*KT+kt], acc, 0,0,0);
    if (lane < 16){
      int col = (w*4+nt)*16 + lane;
#pragma unroll
      for (int q=0; q<4; ++q) gpre[q*512 + col] = acc[q];
    }
  }
}

template<int NF>
static __device__ __forceinline__ void load_wslice(const __half* __restrict__ W,
    f16x8* Bf, int lane, int w)
{
  const f16x8* wb = (const f16x8*)W + (size_t)(w*NF)*64 + lane;
#pragma unroll
  for (int i=0; i<NF; ++i) Bf[i] = wb[(size_t)i*64];
}

// ---- streamed GEMM (decoder): K=256, A = 2 contiguous half-tiles; 16+16 dbuf queue
static __device__ __forceinline__ void mfma_gates_stream(const __half* __restrict__ W,
    const __half* __restrict__ A, float* __restrict__ gpre, int lane, int w)
{
  f16x8 a[8];
#pragma unroll
  for (int kt=0; kt<8; ++kt) a[kt] = *(const f16x8*)(A + (kt*64+lane)*8);
  const f16x8* wb = (const f16x8*)W + (size_t)(w*32)*64 + lane;
  f16x8 q0[16], q1[16];
#pragma unroll
  for (int i=0; i<16; ++i) q0[i] = wb[(size_t)i*64];
#pragma unroll
  for (int i=0; i<16; ++i) q1[i] = wb[(size_t)(16+i)*64];
#pragma unroll
  for (int nt=0; nt<2; ++nt){
    f32x4 acc = {0.f,0.f,0.f,0.f};
#pragma unroll
    for (int kt=0; kt<8; ++kt)
      acc = __builtin_amdgcn_mfma_f32_16x16x32_f16(a[kt], q0[nt*8+kt], acc, 0,0,0);
    if (lane < 16){
      int col = (w*4+nt)*16 + lane;
#pragma unroll
      for (int q=0; q<4; ++q) gpre[q*512 + col] = acc[q];
    }
  }
#pragma unroll
  for (int nt=0; nt<2; ++nt){
    f32x4 acc = {0.f,0.f,0.f,0.f};
#pragma unroll
    for (int kt=0; kt<8; ++kt)
      acc = __builtin_amdgcn_mfma_f32_16x16x32_f16(a[kt], q1[nt*8+kt], acc, 0,0,0);
    if (lane < 16){
      int col = (w*4+nt+2)*16 + lane;
#pragma unroll
      for (int q=0; q<4; ++q) gpre[q*512 + col] = acc[q];
    }
  }
}

// ---------------- weight prep: fp32 -> MFMA B-fragment fp16 layouts ----------------
// B-frag: element (col = nt*16 + (l&15), k = kt*32 + (l>>4)*8 + j) at [nt][kt][l][j]
__global__ void prep_kernel(
    const float* __restrict__ eWih0,  const float* __restrict__ eWhh0,
    const float* __restrict__ eWih12, const float* __restrict__ eWhh12,
    const float* __restrict__ aW,
    const float* __restrict__ dWih0,  const float* __restrict__ dWhh0,
    const float* __restrict__ dWih12, const float* __restrict__ dWhh12,
    const float* __restrict__ oW,
    __half* __restrict__ wE0, __half* __restrict__ wE1, __half* __restrict__ wE2,
    __half* __restrict__ wD0, __half* __restrict__ wD1, __half* __restrict__ wD2,
    __half* __restrict__ wAh, float* __restrict__ wAe, float* __restrict__ wOT,
    float* __restrict__ dW2)
{
  int id = blockIdx.x*blockDim.x + threadIdx.x;
  if (id < 65536){                                   // wE0: K=128 (h only), KT=4
    int m=id, j=m&7, l=(m>>3)&63, kt=(m>>9)&3, nt=m>>11;
    int col = nt*16 + (l&15), k = kt*32 + ((l>>4)<<3) + j;
    wE0[m] = __float2half(eWhh0[col*128 + k]); return;
  }
  id -= 65536;
  if (id < 5*131072){                                // wE1,wE2,wD0,wD1,wD2: K=256, KT=8
    int seg = id >> 17, m = id & 131071;
    int j=m&7, l=(m>>3)&63, kt=(m>>9)&7, nt=m>>12;
    int col = nt*16 + (l&15), k = kt*32 + ((l>>4)<<3) + j;
    float v;
    if (seg==0)      v = (k<128)? eWih12[col*128+k]         : eWhh12[col*128 + (k-128)];
    else if (seg==1) v = (k<128)? eWih12[65536+col*128+k]   : eWhh12[65536 + col*128 + (k-128)];
    else if (seg==2) v = (k<128)? dWih0[col*130 + 2 + k]    : dWhh0[col*128 + (k-128)];
    else if (seg==3) v = (k<128)? dWih12[col*128+k]         : dWhh12[col*128 + (k-128)];
    else             v = (k<128)? dWih12[65536+col*128+k]   : dWhh12[65536 + col*128 + (k-128)];
    __half* dst = (seg==0)?wE1:(seg==1)?wE2:(seg==2)?wD0:(seg==3)?wD1:wD2;
    dst[m] = __float2half(v); return;
  }
  id -= 5*131072;
  if (id < 16384){                                   // wAh: attn_W[:, :H], K=128, 8 nt x 4 kt
    int m=id, j=m&7, l=(m>>3)&63, kt=(m>>9)&3, nt=m>>11;
    int col = nt*16 + (l&15), k = kt*32 + ((l>>4)<<3) + j;
    wAh[m] = __float2half(aW[col*256 + k]); return;
  }
  id -= 16384;
  if (id < 16384){ int k=id>>7, jq=id&127; wAe[id] = aW[jq*256 + 128 + k]; return; }  // [k][j] f32
  id -= 16384;
  if (id < 512){ int k=id>>1, jo=id&1; wOT[id] = oW[jo*256 + k]; return; }            // [k][2] f32
  id -= 512;
  if (id < 1024){ int col=id>>1, ki=id&1; dW2[id] = dWih0[col*130 + ki]; return; }    // [col][2] f32
}

// ---------------- main persistent kernel: 256 blocks x 512 thr, 4 batch rows each ----------------
__global__ __launch_bounds__(512, 2) void seq2seq_main(
    const float* __restrict__ x, const float* __restrict__ prev_y,
    const float* __restrict__ enc_b0, const float* __restrict__ enc_b12,
    const float* __restrict__ attn_b, const float* __restrict__ vW,
    const float* __restrict__ dec_b0, const float* __restrict__ dec_b12,
    const float* __restrict__ out_b, const float* __restrict__ eWih0,
    __half* __restrict__ hsA, __half* __restrict__ hsB,
    const __half* __restrict__ wE0, const __half* __restrict__ wE1, const __half* __restrict__ wE2,
    const __half* __restrict__ wD0, const __half* __restrict__ wD1, const __half* __restrict__ wD2,
    const __half* __restrict__ wAh, const float* __restrict__ wAe, const float* __restrict__ wOT,
    const float* __restrict__ dW2, float* __restrict__ dout)
{
  // Afrag half-tiles (2048 halfs each): ht0 = input/weighted, ht1 = h0, ht2 = h1, ht3 = h2
  __shared__ __align__(16) __half Afrag[4*2048];
  __shared__ __align__(16) float gpre[4*512];
  __shared__ __align__(16) float hw[4*256];          // [r][h2(128)|weighted(128)]
  __shared__ __align__(16) float cst[3][512];
  __shared__ float scb[4][64];
  __shared__ float xc[2][4][2];
  __shared__ float po[4][2];
  __shared__ float vwl[128];
  extern __shared__ __align__(16) __half dynLds[];
  __half* ep16 = dynLds;                             // [256][EPS]
  __half* wAhL = dynLds + 256*EPS;                   // [16384]

  const int tid  = threadIdx.x;
  const int w    = tid >> 6;
  const int lane = tid & 63;
  const int rr   = tid >> 6;      // row for tid<256 phases
  const int b4   = blockIdx.x * 4;

  // pointwise LSTM cell for 2 adjacent cols (j, j+1); writes h into hdest half-tile
  auto cellpw = [&](int r, int j, const float* __restrict__ bias, float* __restrict__ crow,
                    const float* __restrict__ foldW, const float* __restrict__ fv,
                    __half* hdest, __half* hsd, float* hwd){
    const float* gpr = gpre + r*512;
    float2 g0 = *(const float2*)(gpr + j);
    float2 g1 = *(const float2*)(gpr + j + 128);
    float2 g2 = *(const float2*)(gpr + j + 256);
    float2 g3 = *(const float2*)(gpr + j + 384);
    float2 b0 = *(const float2*)(bias + j);
    float2 b1 = *(const float2*)(bias + j + 128);
    float2 b2 = *(const float2*)(bias + j + 256);
    float2 b3 = *(const float2*)(bias + j + 384);
    g0.x+=b0.x; g0.y+=b0.y; g1.x+=b1.x; g1.y+=b1.y;
    g2.x+=b2.x; g2.y+=b2.y; g3.x+=b3.x; g3.y+=b3.y;
    if (foldW){                                      // rank-2 input fold (x or prev_out)
      float a0=fv[0], a1=fv[1];
      float4 f0 = *(const float4*)(foldW + 2*j);
      float4 f1 = *(const float4*)(foldW + 2*j + 256);
      float4 f2 = *(const float4*)(foldW + 2*j + 512);
      float4 f3 = *(const float4*)(foldW + 2*j + 768);
      g0.x += a0*f0.x + a1*f0.y;  g0.y += a0*f0.z + a1*f0.w;
      g1.x += a0*f1.x + a1*f1.y;  g1.y += a0*f1.z + a1*f1.w;
      g2.x += a0*f2.x + a1*f2.y;  g2.y += a0*f2.z + a1*f2.w;
      g3.x += a0*f3.x + a1*f3.y;  g3.y += a0*f3.z + a1*f3.w;
    }
    float2 c = *(const float2*)(crow + j);
    float2 cn, hn;
    cn.x = fmaf(sigm(g1.x), c.x, sigm(g0.x)*tanh_fast(g2.x));
    cn.y = fmaf(sigm(g1.y), c.y, sigm(g0.y)*tanh_fast(g2.y));
    hn.x = sigm(g3.x)*tanh_fast(cn.x);
    hn.y = sigm(g3.y)*tanh_fast(cn.y);
    *(float2*)(crow + j) = cn;
    __half2 hh = __floats2half2_rn(hn.x, hn.y);
    *(__half2*)(hdest + slotk(r, j)) = hh;
    if (hsd) *(__half2*)hsd = hh;
    if (hwd) *(float2*)(hwd + j) = make_float2(hn.x, hn.y);
  };

  // ================= encoder: 3 LSTM layers, weights register-resident =================
  const __half* Wenc[3] = {wE0, wE1, wE2};
  const float*  Benc[3] = {enc_b0, enc_b12, enc_b12 + 512};
  const __half* hsIn[3] = {nullptr, hsA, hsB};
  __half* hsOut[3]      = {hsA, hsB, hsA};   // layer2 overwrites hsA (layer0 data dead)

  f16x8 Bf[32];
  for (int layer=0; layer<3; ++layer){
    if (layer==0) load_wslice<16>(wE0, Bf, lane, w);
    else          load_wslice<32>(Wenc[layer], Bf, lane, w);
    __half* hbuf = Afrag + (1+layer)*2048;
    if (tid < 256){
      *(u32*)(hbuf + slotk(rr, 2*lane)) = 0u;                  // h = 0
      *(float2*)(&cst[layer][rr*128 + 2*lane]) = make_float2(0.f, 0.f);
    } else {
      int idx = tid - 256;
      if (layer==0){
        if (idx < 8){ int r=idx>>1, xi=idx&1; xc[0][r][xi] = x[((size_t)(b4+r)*SEQ + 0)*2 + xi]; }
      } else {
        int r = idx>>6, dp = idx&63;
        u32 hv = *((const u32*)hsIn[layer] + ((size_t)(b4+r)*SEQ + 0)*64 + dp);
        *(u32*)(Afrag + slotk(r, 2*dp)) = hv;
      }
    }
    __syncthreads();
    for (int t=0; t<SEQ; ++t){
      if (layer==0) mfma_gates_reg<4>(Bf, hbuf,  hbuf, gpre, lane, w);
      else          mfma_gates_reg<8>(Bf, Afrag, hbuf, gpre, lane, w);
      __syncthreads();
      if (tid < 256){
        __half* hsd = hsOut[layer] + ((size_t)(b4+rr)*SEQ + t)*HID + 2*lane;
        cellpw(rr, 2*lane, Benc[layer], &cst[layer][rr*128],
               (layer==0)? eWih0 : nullptr, xc[t&1][rr], hbuf, hsd, nullptr);
      } else if (t+1 < SEQ){
        int idx = tid - 256;
        if (layer==0){
          if (idx < 8){ int r=idx>>1, xi=idx&1; xc[(t+1)&1][r][xi] = x[((size_t)(b4+r)*SEQ + t+1)*2 + xi]; }
        } else {
          int r = idx>>6, dp = idx&63;
          u32 hv = *((const u32*)hsIn[layer] + ((size_t)(b4+r)*SEQ + t+1)*64 + dp);
          *(u32*)(Afrag + slotk(r, 2*dp)) = hv;
        }
      }
      __syncthreads();
    }
  }
  __syncthreads();

  // ================= enc-side attention projection (once) =================
  {
    int rs = tid>>1, r = rs>>6, s = rs&63, jh = tid&1;
    const u32* arow = (const u32*)hsA + ((size_t)(b4+r)*SEQ + s)*64;
    u32 a[64];
#pragma unroll
    for (int i=0;i<16;++i){
      uint4 v = ((const uint4*)arow)[i];
      a[4*i]=v.x; a[4*i+1]=v.y; a[4*i+2]=v.z; a[4*i+3]=v.w;
    }
    float acc[64];
    const float* ab = attn_b + jh*64;
#pragma unroll
    for (int jq=0;jq<64;++jq) acc[jq] = ab[jq];
    for (int kp=0; kp<64; ++kp){
      float2 af = __half22float2(*(const __half2*)&a[kp]);
      const float* w0 = wAe + (size_t)(2*kp)*HID + jh*64;
      const float* w1 = w0 + HID;
#pragma unroll
      for (int jq=0;jq<64;++jq) acc[jq] = fmaf(af.x, w0[jq], acc[jq]);
#pragma unroll
      for (int jq=0;jq<64;++jq) acc[jq] = fmaf(af.y, w1[jq], acc[jq]);
    }
    __half2* ep = (__half2*)(ep16 + (size_t)rs*EPS + jh*64);
#pragma unroll
    for (int p=0;p<32;++p) ep[p] = __floats2half2_rn(acc[2*p], acc[2*p+1]);
  }
  // decoder prologue
  if (tid < 8){ po[tid>>1][tid&1] = prev_y[(b4 + (tid>>1))*2 + (tid&1)]; }
  if (tid < 128) vwl[tid] = vW[tid];
  for (int i=tid; i<8192; i+=512) ((u32*)wAhL)[i] = ((const u32*)wAh)[i];
  __syncthreads();

  // ================= decoder: 24 autoregressive steps =================
  for (int t=0; t<TOUT; ++t){
    {  // hproj = h2 @ attn_Wh (B from LDS); wave w owns ntile w of 8
      f16x8 a[4], bw[4];
#pragma unroll
      for (int kt=0;kt<4;++kt) a[kt]  = *(const f16x8*)(Afrag + 3*2048 + (kt*64+lane)*8);
#pragma unroll
      for (int kt=0;kt<4;++kt) bw[kt] = *(const f16x8*)(wAhL + ((w*4+kt)*64+lane)*8);
      f32x4 acc = {0.f,0.f,0.f,0.f};
#pragma unroll
      for (int kt=0;kt<4;++kt)
        acc = __builtin_amdgcn_mfma_f32_16x16x32_f16(a[kt], bw[kt], acc, 0,0,0);
      if (lane < 16){
        int col = w*16 + lane;
#pragma unroll
        for (int q=0;q<4;++q) gpre[q*512+col] = acc[q];
      }
    }
    __syncthreads();
    {  // scores: thread (rs, jh)
      int rs = tid>>1, r = rs>>6, s = rs&63, jh = tid&1;
      const __half2* ep = (const __half2*)(ep16 + (size_t)rs*EPS + jh*64);
      const float* hp = gpre + r*512 + jh*64;
      float s_ = 0.f;
#pragma unroll
      for (int i=0;i<32;++i){
        float2 e = __half22float2(ep[i]);
        s_ = fmaf(tanh_fast(e.x + hp[2*i]),   vwl[jh*64 + 2*i],   s_);
        s_ = fmaf(tanh_fast(e.y + hp[2*i+1]), vwl[jh*64 + 2*i+1], s_);
      }
      s_ += __shfl_xor(s_, 1);
      if (jh==0) scb[r][s] = s_;
    }
    __syncthreads();
    if (tid < 256){   // softmax + weighted -> ht0 + hw
      float sv = scb[rr][lane];
      float mx = sv;
#pragma unroll
      for (int off=32; off; off>>=1) mx = fmaxf(mx, __shfl_xor(mx, off));
      float ev = __expf(sv - mx);
      float sm = ev;
#pragma unroll
      for (int off=32; off; off>>=1) sm += __shfl_xor(sm, off);
      scb[rr][lane] = ev / sm;
      const u32* eb = (const u32*)hsA + ((size_t)(b4+rr)*SEQ)*64 + lane;
      float a0=0.f, a1=0.f;
#pragma unroll 8
      for (int s2=0; s2<64; ++s2){
        float wgt = scb[rr][s2];
        float2 af = __half22float2(*(const __half2*)&eb[(size_t)s2*64]);
        a0 = fmaf(wgt, af.x, a0); a1 = fmaf(wgt, af.y, a1);
      }
      int j = 2*lane;
      *(__half2*)(Afrag + slotk(rr, j)) = __floats2half2_rn(a0, a1);
      *(float2*)(hw + rr*256 + 128 + j) = make_float2(a0, a1);
    }
    __syncthreads();
    mfma_gates_stream(wD0, Afrag,          gpre, lane, w);   // [weighted | h0]
    __syncthreads();
    if (tid < 256) cellpw(rr, 2*lane, dec_b0, &cst[0][rr*128], dW2, po[rr],
                          Afrag + 1*2048, nullptr, nullptr);
    __syncthreads();
    mfma_gates_stream(wD1, Afrag + 1*2048, gpre, lane, w);   // [h0 | h1]
    __syncthreads();
    if (tid < 256) cellpw(rr, 2*lane, dec_b12, &cst[1][rr*128], nullptr, nullptr,
                          Afrag + 2*2048, nullptr, nullptr);
    __syncthreads();
    mfma_gates_stream(wD2, Afrag + 2*2048, gpre, lane, w);   // [h1 | h2]
    __syncthreads();
    if (tid < 256) cellpw(rr, 2*lane, dec_b12 + 512, &cst[2][rr*128], nullptr, nullptr,
                          Afrag + 3*2048, nullptr, hw + rr*256);
    __syncthreads();
    if (tid < 256){   // output head
      float4 hv = *(const float4*)(hw + rr*256 + lane*4);
      float4 w0 = *(const float4*)(wOT + 8*lane);
      float4 w1 = *(const float4*)(wOT + 8*lane + 4);
      float o0 = hv.x*w0.x + hv.y*w0.z + hv.z*w1.x + hv.w*w1.z;
      float o1 = hv.x*w0.y + hv.y*w0.w + hv.z*w1.y + hv.w*w1.w;
#pragma unroll
      for (int off=32; off; off>>=1){ o0 += __shfl_down(o0,off); o1 += __shfl_down(o1,off); }
      if (lane==0){
        float v0 = o0 + out_b[0], v1 = o1 + out_b[1];
        size_t oi = ((size_t)t*BATCH + b4 + rr)*2;
        dout[oi] = v0; dout[oi+1] = v1;
        po[rr][0] = v0; po[rr][1] = v1;
      }
    }
    __syncthreads();
  }
}

extern "C" void kernel_launch(void* const* d_in, const int* in_sizes, int n_in,
                              void* d_out, int out_size, void* d_ws, size_t ws_size,
                              hipStream_t stream) {
  const float* x      = (const float*)d_in[0];
  const float* prev_y = (const float*)d_in[1];
  const float* eWih0  = (const float*)d_in[2];
  const float* eWhh0  = (const float*)d_in[3];
  const float* eb0    = (const float*)d_in[4];
  const float* eWih12 = (const float*)d_in[5];
  const float* eWhh12 = (const float*)d_in[6];
  const float* eb12   = (const float*)d_in[7];
  const float* aW     = (const float*)d_in[8];
  const float* ab     = (const float*)d_in[9];
  const float* vW     = (const float*)d_in[10];
  const float* dWih0  = (const float*)d_in[11];
  const float* dWhh0  = (const float*)d_in[12];
  const float* db0    = (const float*)d_in[13];
  const float* dWih12 = (const float*)d_in[14];
  const float* dWhh12 = (const float*)d_in[15];
  const float* db12   = (const float*)d_in[16];
  const float* oW     = (const float*)d_in[17];
  const float* ob     = (const float*)d_in[18];

  __half* wE0 = (__half*)d_ws;           // 65536 halfs
  __half* wE1 = wE0 + 65536;             // 131072 each
  __half* wE2 = wE1 + 131072;
  __half* wD0 = wE2 + 131072;
  __half* wD1 = wD0 + 131072;
  __half* wD2 = wD1 + 131072;
  __half* wAh = wD2 + 131072;            // 16384
  float*  wAe = (float*)(wAh + 16384);   // 16384 f32
  float*  wOT = wAe + 16384;             // 512 f32
  float*  dW2 = wOT + 512;               // 1024 f32
  __half* hsA = (__half*)(dW2 + 1024);
  __half* hsB = hsA + (size_t)BATCH*SEQ*HID;

  const int prepN = 65536 + 5*131072 + 16384 + 16384 + 512 + 1024;
  prep_kernel<<<(prepN + 255)/256, 256, 0, stream>>>(
      eWih0, eWhh0, eWih12, eWhh12, aW, dWih0, dWhh0, dWih12, dWhh12, oW,
      wE0, wE1, wE2, wD0, wD1, wD2, wAh, wAe, wOT, dW2);

  const int dynBytes = 256*EPS*2 + 16384*2;   // ep16 (67,584 B) + wAhL (32,768 B)
  hipFuncSetAttribute(reinterpret_cast<const void*>(seq2seq_main),
                      hipFuncAttributeMaxDynamicSharedMemorySize, dynBytes);

  seq2seq_main<<<256, 512, dynBytes, stream>>>(
      x, prev_y, eb0, eb12, ab, vW, db0, db12, ob, eWih0,
      hsA, hsB, wE0, wE1, wE2, wD0, wD1, wD2, wAh, wAe, wOT, dW2,
      (float*)d_out);
}